// Round 1
// baseline (488.420 us; speedup 1.0000x reference)
//
#include <hip/hip_runtime.h>
#include <stdint.h>

// Problem constants: B=2, S=2048, HIDDEN=1024, NH=16, D=64
// M = B*S = 4096, N1 = 3072, K = 1024, N2 = 1024, BH = 32

#define DEV static __device__ __forceinline__

typedef unsigned short u16;
typedef __attribute__((ext_vector_type(4))) float f32x4;
typedef __bf16 bf16x8 __attribute__((ext_vector_type(8)));
typedef __attribute__((ext_vector_type(8))) unsigned short u16x8;
typedef __attribute__((ext_vector_type(4))) unsigned short u16x4;

DEV u16 f2bf(float f) {
    unsigned u = __builtin_bit_cast(unsigned, f);
    u += 0x7fffu + ((u >> 16) & 1u);
    return (u16)(u >> 16);
}
DEV float bf2f(u16 h) {
    unsigned u = ((unsigned)h) << 16;
    return __builtin_bit_cast(float, u);
}

// async global->LDS, 16B per lane. LDS dest must be wave-uniform base + lane*16.
DEV void async_copy16(const void* g, void* l) {
    __builtin_amdgcn_global_load_lds(
        (__attribute__((address_space(1))) void*)(g),
        (__attribute__((address_space(3))) void*)(l), 16, 0, 0);
}

// ---------------- elementwise cast kernels ----------------

__global__ __launch_bounds__(256) void cast_f32_bf16(
    const float* __restrict__ src, u16* __restrict__ dst, int n4) {
    int i = blockIdx.x * 256 + threadIdx.x;
    if (i >= n4) return;
    f32x4 v = *(const f32x4*)(src + (size_t)i * 4);
    u16x4 o;
#pragma unroll
    for (int j = 0; j < 4; j++) o[j] = f2bf(v[j]);
    *(u16x4*)(dst + (size_t)i * 4) = o;
}

// src [rows][cols] fp32  ->  dst [cols][rows] bf16
__global__ __launch_bounds__(256) void transpose_cast(
    const float* __restrict__ src, u16* __restrict__ dst, int rows, int cols) {
    __shared__ float tile[32][33];
    int c0 = blockIdx.x * 32, r0 = blockIdx.y * 32;
    int tx = threadIdx.x, ty = threadIdx.y;  // block (32,8)
#pragma unroll
    for (int i = 0; i < 4; i++)
        tile[ty + i * 8][tx] = src[(size_t)(r0 + ty + i * 8) * cols + c0 + tx];
    __syncthreads();
#pragma unroll
    for (int i = 0; i < 4; i++)
        dst[(size_t)(c0 + ty + i * 8) * rows + r0 + tx] = f2bf(tile[tx][ty + i * 8]);
}

// ---------------- 128x128 bf16 MFMA GEMM core ----------------
// A [M][K] bf16 row-major, Bt [N][K] bf16 row-major (i.e. B transposed).
// 256 threads = 4 waves in 2x2; each wave owns 64x64 (4x4 MFMA 16x16x32 tiles).
DEV void gemm128_core(const u16* __restrict__ A, const u16* __restrict__ Bt,
                      int m0, int n0, int Kdim, u16* As, u16* Bs,
                      f32x4 (*acc)[4]) {
    const int t = threadIdx.x;
    const int wave = t >> 6;
    const int lane = t & 63;
    const int quad = lane >> 4;
    const int l16 = lane & 15;
    const int wr = wave >> 1;
    const int wc = wave & 1;

    for (int kt = 0; kt < Kdim; kt += 32) {
#pragma unroll
        for (int i = 0; i < 2; i++) {
            int idx = i * 256 + t;
            int row = idx >> 2, kc = idx & 3;
            async_copy16(A + (size_t)(m0 + row) * Kdim + kt + kc * 8, &As[idx * 8]);
            async_copy16(Bt + (size_t)(n0 + row) * Kdim + kt + kc * 8, &Bs[idx * 8]);
        }
        __syncthreads();
        bf16x8 af[4], bfr[4];
#pragma unroll
        for (int mt = 0; mt < 4; mt++)
            af[mt] = *(const bf16x8*)&As[(wr * 64 + mt * 16 + l16) * 32 + quad * 8];
#pragma unroll
        for (int nt = 0; nt < 4; nt++)
            bfr[nt] = *(const bf16x8*)&Bs[(wc * 64 + nt * 16 + l16) * 32 + quad * 8];
#pragma unroll
        for (int mt = 0; mt < 4; mt++)
#pragma unroll
            for (int nt = 0; nt < 4; nt++)
                acc[mt][nt] = __builtin_amdgcn_mfma_f32_16x16x32_bf16(
                    af[mt], bfr[nt], acc[mt][nt], 0, 0, 0);
        __syncthreads();
    }
}

// GEMM1: qkv projection, epilogue scatters into q/k/v [bh][s][d] bf16
__global__ __launch_bounds__(256) void gemm_qkv(
    const u16* __restrict__ A, const u16* __restrict__ Bt,
    u16* __restrict__ qb, u16* __restrict__ kb, u16* __restrict__ vb) {
    __shared__ __align__(16) u16 As[128 * 32];
    __shared__ __align__(16) u16 Bs[128 * 32];
    const int m0 = blockIdx.y * 128;
    const int n0 = blockIdx.x * 128;
    f32x4 acc[4][4];
#pragma unroll
    for (int i = 0; i < 4; i++)
#pragma unroll
        for (int j = 0; j < 4; j++) acc[i][j] = {0.f, 0.f, 0.f, 0.f};

    gemm128_core(A, Bt, m0, n0, 1024, As, Bs, acc);

    const int t = threadIdx.x;
    const int wave = t >> 6, lane = t & 63;
    const int quad = lane >> 4, l16 = lane & 15;
    const int wr = wave >> 1, wc = wave & 1;
#pragma unroll
    for (int nt = 0; nt < 4; nt++) {
        int nn = n0 + wc * 64 + nt * 16 + l16;
        int tsel = nn >> 10;           // 0=q 1=k 2=v
        int rem = nn & 1023;
        int h = rem >> 6, d = rem & 63;
        u16* dst = tsel == 0 ? qb : (tsel == 1 ? kb : vb);
#pragma unroll
        for (int mt = 0; mt < 4; mt++) {
#pragma unroll
            for (int r = 0; r < 4; r++) {
                int mm = m0 + wr * 64 + mt * 16 + quad * 4 + r;
                int b = mm >> 11, s = mm & 2047;
                dst[(size_t)((b * 16 + h) * 2048 + s) * 64 + d] = f2bf(acc[mt][nt][r]);
            }
        }
    }
}

// GEMM2: out = values @ w_o, fp32 output
__global__ __launch_bounds__(256) void gemm_out(
    const u16* __restrict__ A, const u16* __restrict__ Bt,
    float* __restrict__ out) {
    __shared__ __align__(16) u16 As[128 * 32];
    __shared__ __align__(16) u16 Bs[128 * 32];
    const int m0 = blockIdx.y * 128;
    const int n0 = blockIdx.x * 128;
    f32x4 acc[4][4];
#pragma unroll
    for (int i = 0; i < 4; i++)
#pragma unroll
        for (int j = 0; j < 4; j++) acc[i][j] = {0.f, 0.f, 0.f, 0.f};

    gemm128_core(A, Bt, m0, n0, 1024, As, Bs, acc);

    const int t = threadIdx.x;
    const int wave = t >> 6, lane = t & 63;
    const int quad = lane >> 4, l16 = lane & 15;
    const int wr = wave >> 1, wc = wave & 1;
#pragma unroll
    for (int nt = 0; nt < 4; nt++) {
        int nn = n0 + wc * 64 + nt * 16 + l16;
#pragma unroll
        for (int mt = 0; mt < 4; mt++) {
#pragma unroll
            for (int r = 0; r < 4; r++) {
                int mm = m0 + wr * 64 + mt * 16 + quad * 4 + r;
                out[(size_t)mm * 1024 + nn] = acc[mt][nt][r];
            }
        }
    }
}

// ---------------- attention passes ----------------
// Pass 1: per (bh, 16-row q tile), one wave sweeps all 2048 k columns,
// computing online row-max m and row-sum l of exp(s-m). Stores m and 1/l.
__global__ __launch_bounds__(256) void attn_pass1(
    const u16* __restrict__ qb, const u16* __restrict__ kb,
    float* __restrict__ m_ws, float* __restrict__ li_ws) {
    const int wid = blockIdx.x * 4 + (threadIdx.x >> 6);  // 0..4095
    const int bh = wid >> 7;
    const int qt = wid & 127;
    const int lane = threadIdx.x & 63;
    const int quad = lane >> 4, l16 = lane & 15;

    const u16* Qr = qb + (size_t)(bh * 2048 + qt * 16 + l16) * 64;
    bf16x8 a0 = *(const bf16x8*)&Qr[quad * 8];
    bf16x8 a1 = *(const bf16x8*)&Qr[32 + quad * 8];

    const u16* Kb = kb + (size_t)bh * 2048 * 64;
    float mrun[4], lrun[4];
#pragma unroll
    for (int r = 0; r < 4; r++) { mrun[r] = -1e30f; lrun[r] = 0.f; }

    for (int nt = 0; nt < 128; nt++) {
        const u16* Kr = Kb + (size_t)(nt * 16 + l16) * 64;
        bf16x8 b0 = *(const bf16x8*)&Kr[quad * 8];
        bf16x8 b1 = *(const bf16x8*)&Kr[32 + quad * 8];
        f32x4 acc = {0.f, 0.f, 0.f, 0.f};
        acc = __builtin_amdgcn_mfma_f32_16x16x32_bf16(a0, b0, acc, 0, 0, 0);
        acc = __builtin_amdgcn_mfma_f32_16x16x32_bf16(a1, b1, acc, 0, 0, 0);
#pragma unroll
        for (int r = 0; r < 4; r++) {
            float s = acc[r] * 0.125f;
            float tm = s;
            tm = fmaxf(tm, __shfl_xor(tm, 1));
            tm = fmaxf(tm, __shfl_xor(tm, 2));
            tm = fmaxf(tm, __shfl_xor(tm, 4));
            tm = fmaxf(tm, __shfl_xor(tm, 8));
            float mnew = fmaxf(mrun[r], tm);
            float e = __expf(s - mnew);
            e += __shfl_xor(e, 1);
            e += __shfl_xor(e, 2);
            e += __shfl_xor(e, 4);
            e += __shfl_xor(e, 8);
            lrun[r] = lrun[r] * __expf(mrun[r] - mnew) + e;
            mrun[r] = mnew;
        }
    }
    if (l16 == 0) {
#pragma unroll
        for (int r = 0; r < 4; r++) {
            int row = qt * 16 + quad * 4 + r;
            m_ws[bh * 2048 + row] = mrun[r];
            li_ws[bh * 2048 + row] = 1.0f / lrun[r];
        }
    }
}

// Pass 2: per (bh, 16-col k tile), one wave sweeps all 2048 q rows,
// accumulating colsum[k] = sum_q exp(s[q,k]-m[q]) / l[q].
__global__ __launch_bounds__(256) void attn_pass2(
    const u16* __restrict__ qb, const u16* __restrict__ kb,
    const float* __restrict__ m_ws, const float* __restrict__ li_ws,
    float* __restrict__ cs_ws) {
    const int wid = blockIdx.x * 4 + (threadIdx.x >> 6);
    const int bh = wid >> 7;
    const int ntile = wid & 127;
    const int lane = threadIdx.x & 63;
    const int quad = lane >> 4, l16 = lane & 15;

    const u16* Kr = kb + (size_t)(bh * 2048 + ntile * 16 + l16) * 64;
    bf16x8 b0 = *(const bf16x8*)&Kr[quad * 8];
    bf16x8 b1 = *(const bf16x8*)&Kr[32 + quad * 8];

    const u16* Qb = qb + (size_t)bh * 2048 * 64;
    float cs = 0.f;
    for (int qt = 0; qt < 128; qt++) {
        const u16* Qr = Qb + (size_t)(qt * 16 + l16) * 64;
        bf16x8 a0 = *(const bf16x8*)&Qr[quad * 8];
        bf16x8 a1 = *(const bf16x8*)&Qr[32 + quad * 8];
        f32x4 acc = {0.f, 0.f, 0.f, 0.f};
        acc = __builtin_amdgcn_mfma_f32_16x16x32_bf16(a0, b0, acc, 0, 0, 0);
        acc = __builtin_amdgcn_mfma_f32_16x16x32_bf16(a1, b1, acc, 0, 0, 0);
        f32x4 mv = *(const f32x4*)&m_ws[bh * 2048 + qt * 16 + quad * 4];
        f32x4 lv = *(const f32x4*)&li_ws[bh * 2048 + qt * 16 + quad * 4];
#pragma unroll
        for (int r = 0; r < 4; r++)
            cs += __expf(acc[r] * 0.125f - mv[r]) * lv[r];
    }
    cs += __shfl_xor(cs, 16);
    cs += __shfl_xor(cs, 32);
    if (lane < 16)
        cs_ws[bh * 2048 + ntile * 16 + lane] = cs;
}

// values[b][s][h*64+d] = colsum[bh][s] * v[bh][s][d]  (bf16)
__global__ __launch_bounds__(256) void scale_v(
    const u16* __restrict__ vb, const float* __restrict__ cs_ws,
    u16* __restrict__ valsb) {
    int tid = blockIdx.x * 256 + threadIdx.x;  // 524288 threads, 8 elems each
    int base = tid << 3;
    int bh = base >> 17;           // / (2048*64)
    int rem = base & 131071;
    int s = rem >> 6;
    int d0 = rem & 63;
    float cs = cs_ws[bh * 2048 + s];
    u16x8 v = *(const u16x8*)(vb + (size_t)base);
    u16x8 o;
#pragma unroll
    for (int i = 0; i < 8; i++) o[i] = f2bf(bf2f(v[i]) * cs);
    int b = bh >> 4, h = bh & 15;
    *(u16x8*)(valsb + (size_t)((b * 2048 + s) * 1024) + h * 64 + d0) = o;
}

// ---------------- launch ----------------

extern "C" void kernel_launch(void* const* d_in, const int* in_sizes, int n_in,
                              void* d_out, int out_size, void* d_ws, size_t ws_size,
                              hipStream_t stream) {
    const float* x    = (const float*)d_in[0];   // [2,2048,1024]
    const float* wqkv = (const float*)d_in[1];   // [1024,3072]
    const float* wo   = (const float*)d_in[2];   // [1024,1024]
    float* out = (float*)d_out;                  // [2,2048,1024] fp32
    char* ws = (char*)d_ws;                      // needs ~48.8 MB

    u16* xb      = (u16*)(ws);                   // [4096][1024] bf16
    u16* wqkvT   = (u16*)(ws + 8388608);         // [3072][1024] bf16
    u16* woT     = (u16*)(ws + 14680064);        // [1024][1024] bf16
    u16* qb      = (u16*)(ws + 16777216);        // [32][2048][64] bf16
    u16* kb      = (u16*)(ws + 25165824);
    u16* vb      = (u16*)(ws + 33554432);
    float* m_ws  = (float*)(ws + 41943040);      // [32][2048]
    float* li_ws = (float*)(ws + 42205184);
    float* cs_ws = (float*)(ws + 42467328);
    u16* valsb   = (u16*)(ws + 42729472);        // [4096][1024] bf16

    cast_f32_bf16<<<4096, 256, 0, stream>>>(x, xb, 1048576);
    transpose_cast<<<dim3(96, 32), dim3(32, 8), 0, stream>>>(wqkv, wqkvT, 1024, 3072);
    transpose_cast<<<dim3(32, 32), dim3(32, 8), 0, stream>>>(wo, woT, 1024, 1024);
    gemm_qkv<<<dim3(24, 32), 256, 0, stream>>>(xb, wqkvT, qb, kb, vb);
    attn_pass1<<<1024, 256, 0, stream>>>(qb, kb, m_ws, li_ws);
    attn_pass2<<<1024, 256, 0, stream>>>(qb, kb, m_ws, li_ws, cs_ws);
    scale_v<<<2048, 256, 0, stream>>>(vb, cs_ws, valsb);
    gemm_out<<<dim3(8, 32), 256, 0, stream>>>(valsb, woT, out);
}

// Round 2
// 274.573 us; speedup vs baseline: 1.7788x; 1.7788x over previous
//
#include <hip/hip_runtime.h>
#include <stdint.h>

// Problem constants: B=2, S=2048, HIDDEN=1024, NH=16, D=64
// M = B*S = 4096, N1 = 3072, K = 1024, N2 = 1024, BH = 32

#define DEV static __device__ __forceinline__

typedef unsigned short u16;
typedef __attribute__((ext_vector_type(4))) float f32x4;
typedef __bf16 bf16x8 __attribute__((ext_vector_type(8)));
typedef __attribute__((ext_vector_type(8))) unsigned short u16x8;
typedef __attribute__((ext_vector_type(4))) unsigned short u16x4;

// 0.125 * log2(e): folded into Q so softmax weights are exp2(acc)
#define QSCALE 0.18033688011112042f

DEV u16 f2bf(float f) {
    unsigned u = __builtin_bit_cast(unsigned, f);
    u += 0x7fffu + ((u >> 16) & 1u);
    return (u16)(u >> 16);
}
DEV float bf2f(u16 h) {
    unsigned u = ((unsigned)h) << 16;
    return __builtin_bit_cast(float, u);
}

// async global->LDS, 16B per lane. LDS dest must be wave-uniform base + lane*16.
DEV void async_copy16(const void* g, void* l) {
    __builtin_amdgcn_global_load_lds(
        (__attribute__((address_space(1))) void*)(g),
        (__attribute__((address_space(3))) void*)(l), 16, 0, 0);
}

// ---------------- elementwise cast kernels ----------------

__global__ __launch_bounds__(256) void cast_f32_bf16(
    const float* __restrict__ src, u16* __restrict__ dst, int n4) {
    int i = blockIdx.x * 256 + threadIdx.x;
    if (i >= n4) return;
    f32x4 v = *(const f32x4*)(src + (size_t)i * 4);
    u16x4 o;
#pragma unroll
    for (int j = 0; j < 4; j++) o[j] = f2bf(v[j]);
    *(u16x4*)(dst + (size_t)i * 4) = o;
}

// src [rows][cols] fp32  ->  dst [cols][rows] bf16
__global__ __launch_bounds__(256) void transpose_cast(
    const float* __restrict__ src, u16* __restrict__ dst, int rows, int cols) {
    __shared__ float tile[32][33];
    int c0 = blockIdx.x * 32, r0 = blockIdx.y * 32;
    int tx = threadIdx.x, ty = threadIdx.y;  // block (32,8)
#pragma unroll
    for (int i = 0; i < 4; i++)
        tile[ty + i * 8][tx] = src[(size_t)(r0 + ty + i * 8) * cols + c0 + tx];
    __syncthreads();
#pragma unroll
    for (int i = 0; i < 4; i++)
        dst[(size_t)(c0 + ty + i * 8) * rows + r0 + tx] = f2bf(tile[tx][ty + i * 8]);
}

// ---------------- 128x128 bf16 MFMA GEMM core ----------------
// A [M][K] bf16 row-major, Bt [N][K] bf16 row-major (i.e. B transposed).
// 256 threads = 4 waves in 2x2; each wave owns 64x64 (4x4 MFMA 16x16x32 tiles).
DEV void gemm128_core(const u16* __restrict__ A, const u16* __restrict__ Bt,
                      int m0, int n0, int Kdim, u16* As, u16* Bs,
                      f32x4 (*acc)[4]) {
    const int t = threadIdx.x;
    const int wave = t >> 6;
    const int lane = t & 63;
    const int quad = lane >> 4;
    const int l16 = lane & 15;
    const int wr = wave >> 1;
    const int wc = wave & 1;

    for (int kt = 0; kt < Kdim; kt += 32) {
#pragma unroll
        for (int i = 0; i < 2; i++) {
            int idx = i * 256 + t;
            int row = idx >> 2, kc = idx & 3;
            async_copy16(A + (size_t)(m0 + row) * Kdim + kt + kc * 8, &As[idx * 8]);
            async_copy16(Bt + (size_t)(n0 + row) * Kdim + kt + kc * 8, &Bs[idx * 8]);
        }
        __syncthreads();
        bf16x8 af[4], bfr[4];
#pragma unroll
        for (int mt = 0; mt < 4; mt++)
            af[mt] = *(const bf16x8*)&As[(wr * 64 + mt * 16 + l16) * 32 + quad * 8];
#pragma unroll
        for (int nt = 0; nt < 4; nt++)
            bfr[nt] = *(const bf16x8*)&Bs[(wc * 64 + nt * 16 + l16) * 32 + quad * 8];
#pragma unroll
        for (int mt = 0; mt < 4; mt++)
#pragma unroll
            for (int nt = 0; nt < 4; nt++)
                acc[mt][nt] = __builtin_amdgcn_mfma_f32_16x16x32_bf16(
                    af[mt], bfr[nt], acc[mt][nt], 0, 0, 0);
        __syncthreads();
    }
}

// GEMM1: qkv projection, epilogue scatters into q/k/v [bh][s][d] bf16.
// Q is pre-scaled by QSCALE so attention passes can use exp2 directly.
__global__ __launch_bounds__(256) void gemm_qkv(
    const u16* __restrict__ A, const u16* __restrict__ Bt,
    u16* __restrict__ qb, u16* __restrict__ kb, u16* __restrict__ vb) {
    __shared__ __align__(16) u16 As[128 * 32];
    __shared__ __align__(16) u16 Bs[128 * 32];
    const int m0 = blockIdx.y * 128;
    const int n0 = blockIdx.x * 128;
    f32x4 acc[4][4];
#pragma unroll
    for (int i = 0; i < 4; i++)
#pragma unroll
        for (int j = 0; j < 4; j++) acc[i][j] = {0.f, 0.f, 0.f, 0.f};

    gemm128_core(A, Bt, m0, n0, 1024, As, Bs, acc);

    const int t = threadIdx.x;
    const int wave = t >> 6, lane = t & 63;
    const int quad = lane >> 4, l16 = lane & 15;
    const int wr = wave >> 1, wc = wave & 1;
#pragma unroll
    for (int nt = 0; nt < 4; nt++) {
        int nn = n0 + wc * 64 + nt * 16 + l16;
        int tsel = nn >> 10;           // 0=q 1=k 2=v
        int rem = nn & 1023;
        int h = rem >> 6, d = rem & 63;
        u16* dst = tsel == 0 ? qb : (tsel == 1 ? kb : vb);
        float scl = tsel == 0 ? QSCALE : 1.0f;
#pragma unroll
        for (int mt = 0; mt < 4; mt++) {
#pragma unroll
            for (int r = 0; r < 4; r++) {
                int mm = m0 + wr * 64 + mt * 16 + quad * 4 + r;
                int b = mm >> 11, s = mm & 2047;
                dst[(size_t)((b * 16 + h) * 2048 + s) * 64 + d] = f2bf(acc[mt][nt][r] * scl);
            }
        }
    }
}

// GEMM2: out = values @ w_o, fp32 output
__global__ __launch_bounds__(256) void gemm_out(
    const u16* __restrict__ A, const u16* __restrict__ Bt,
    float* __restrict__ out) {
    __shared__ __align__(16) u16 As[128 * 32];
    __shared__ __align__(16) u16 Bs[128 * 32];
    const int m0 = blockIdx.y * 128;
    const int n0 = blockIdx.x * 128;
    f32x4 acc[4][4];
#pragma unroll
    for (int i = 0; i < 4; i++)
#pragma unroll
        for (int j = 0; j < 4; j++) acc[i][j] = {0.f, 0.f, 0.f, 0.f};

    gemm128_core(A, Bt, m0, n0, 1024, As, Bs, acc);

    const int t = threadIdx.x;
    const int wave = t >> 6, lane = t & 63;
    const int quad = lane >> 4, l16 = lane & 15;
    const int wr = wave >> 1, wc = wave & 1;
#pragma unroll
    for (int nt = 0; nt < 4; nt++) {
        int nn = n0 + wc * 64 + nt * 16 + l16;
#pragma unroll
        for (int mt = 0; mt < 4; mt++) {
#pragma unroll
            for (int r = 0; r < 4; r++) {
                int mm = m0 + wr * 64 + mt * 16 + quad * 4 + r;
                out[(size_t)mm * 1024 + nn] = acc[mt][nt][r];
            }
        }
    }
}

// ---------------- attention passes ----------------
// No max subtraction: scores are O(+-5), exp2 args safely in fp32 range, and
// exp(s)/sum(exp(s)) == softmax exactly. Q pre-scaled by 0.125*log2e.
//
// Pass 1: per wave, 32 q-rows (2 chunks of 16); sweep all 128 k-tiles.
// lsum[q] = sum_k exp2(score). No in-loop cross-lane ops; row reduction at end.
__global__ __launch_bounds__(256) void attn_pass1(
    const u16* __restrict__ qb, const u16* __restrict__ kb,
    float* __restrict__ li_ws) {
    const int wave = threadIdx.x >> 6;
    const int lane = threadIdx.x & 63;
    const int quad = lane >> 4, l16 = lane & 15;
    const int bh = blockIdx.x >> 4;                    // 32 bh x 16 blocks
    const int q0 = (blockIdx.x & 15) * 128 + wave * 32;

    const u16* Qb = qb + (size_t)bh * 2048 * 64;
    bf16x8 a[2][2];
#pragma unroll
    for (int c = 0; c < 2; c++) {
        const u16* Qr = Qb + (size_t)(q0 + c * 16 + l16) * 64;
        a[c][0] = *(const bf16x8*)&Qr[quad * 8];
        a[c][1] = *(const bf16x8*)&Qr[32 + quad * 8];
    }
    const u16* Kb = kb + (size_t)bh * 2048 * 64;
    float lsum[2][4] = {{0.f, 0.f, 0.f, 0.f}, {0.f, 0.f, 0.f, 0.f}};

#pragma unroll 4
    for (int nt = 0; nt < 128; nt++) {
        const u16* Kr = Kb + (size_t)(nt * 16 + l16) * 64;
        bf16x8 b0 = *(const bf16x8*)&Kr[quad * 8];
        bf16x8 b1 = *(const bf16x8*)&Kr[32 + quad * 8];
#pragma unroll
        for (int c = 0; c < 2; c++) {
            f32x4 acc = {0.f, 0.f, 0.f, 0.f};
            acc = __builtin_amdgcn_mfma_f32_16x16x32_bf16(a[c][0], b0, acc, 0, 0, 0);
            acc = __builtin_amdgcn_mfma_f32_16x16x32_bf16(a[c][1], b1, acc, 0, 0, 0);
#pragma unroll
            for (int r = 0; r < 4; r++)
                lsum[c][r] += __builtin_amdgcn_exp2f(acc[r]);
        }
    }
    // reduce across the 16 lanes of each quad (columns), once
#pragma unroll
    for (int c = 0; c < 2; c++)
#pragma unroll
        for (int r = 0; r < 4; r++) {
            float v = lsum[c][r];
            v += __shfl_xor(v, 1);
            v += __shfl_xor(v, 2);
            v += __shfl_xor(v, 4);
            v += __shfl_xor(v, 8);
            lsum[c][r] = v;
        }
    if (l16 == 0) {
#pragma unroll
        for (int c = 0; c < 2; c++)
#pragma unroll
            for (int r = 0; r < 4; r++)
                li_ws[bh * 2048 + q0 + c * 16 + quad * 4 + r] = 1.0f / lsum[c][r];
    }
}

// Pass 2: per wave, 32 k-cols (2 chunks of 16); sweep all 128 q-tiles.
// colsum[k] = sum_q exp2(score[q,k]) / l[q]. Quad reduction at end only.
__global__ __launch_bounds__(256) void attn_pass2(
    const u16* __restrict__ qb, const u16* __restrict__ kb,
    const float* __restrict__ li_ws, float* __restrict__ cs_ws) {
    const int wave = threadIdx.x >> 6;
    const int lane = threadIdx.x & 63;
    const int quad = lane >> 4, l16 = lane & 15;
    const int bh = blockIdx.x >> 4;
    const int k0 = (blockIdx.x & 15) * 128 + wave * 32;

    const u16* Kb = kb + (size_t)bh * 2048 * 64;
    bf16x8 b[2][2];
#pragma unroll
    for (int c = 0; c < 2; c++) {
        const u16* Kr = Kb + (size_t)(k0 + c * 16 + l16) * 64;
        b[c][0] = *(const bf16x8*)&Kr[quad * 8];
        b[c][1] = *(const bf16x8*)&Kr[32 + quad * 8];
    }
    const u16* Qb = qb + (size_t)bh * 2048 * 64;
    const float* li_b = li_ws + bh * 2048;
    float cs[2] = {0.f, 0.f};

#pragma unroll 4
    for (int qt = 0; qt < 128; qt++) {
        const u16* Qr = Qb + (size_t)(qt * 16 + l16) * 64;
        bf16x8 a0 = *(const bf16x8*)&Qr[quad * 8];
        bf16x8 a1 = *(const bf16x8*)&Qr[32 + quad * 8];
        f32x4 li = *(const f32x4*)&li_b[qt * 16 + quad * 4];
#pragma unroll
        for (int c = 0; c < 2; c++) {
            f32x4 acc = {0.f, 0.f, 0.f, 0.f};
            acc = __builtin_amdgcn_mfma_f32_16x16x32_bf16(a0, b[c][0], acc, 0, 0, 0);
            acc = __builtin_amdgcn_mfma_f32_16x16x32_bf16(a1, b[c][1], acc, 0, 0, 0);
#pragma unroll
            for (int r = 0; r < 4; r++)
                cs[c] += __builtin_amdgcn_exp2f(acc[r]) * li[r];
        }
    }
#pragma unroll
    for (int c = 0; c < 2; c++) {
        float v = cs[c];
        v += __shfl_xor(v, 16);
        v += __shfl_xor(v, 32);
        if (lane < 16) cs_ws[bh * 2048 + k0 + c * 16 + lane] = v;
    }
}

// values[b][s][h*64+d] = colsum[bh][s] * v[bh][s][d]  (bf16)
__global__ __launch_bounds__(256) void scale_v(
    const u16* __restrict__ vb, const float* __restrict__ cs_ws,
    u16* __restrict__ valsb) {
    int tid = blockIdx.x * 256 + threadIdx.x;  // 524288 threads, 8 elems each
    int base = tid << 3;
    int bh = base >> 17;           // / (2048*64)
    int rem = base & 131071;
    int s = rem >> 6;
    int d0 = rem & 63;
    float cs = cs_ws[bh * 2048 + s];
    u16x8 v = *(const u16x8*)(vb + (size_t)base);
    u16x8 o;
#pragma unroll
    for (int i = 0; i < 8; i++) o[i] = f2bf(bf2f(v[i]) * cs);
    int b = bh >> 4, h = bh & 15;
    *(u16x8*)(valsb + (size_t)((b * 2048 + s) * 1024) + h * 64 + d0) = o;
}

// ---------------- launch ----------------

extern "C" void kernel_launch(void* const* d_in, const int* in_sizes, int n_in,
                              void* d_out, int out_size, void* d_ws, size_t ws_size,
                              hipStream_t stream) {
    const float* x    = (const float*)d_in[0];   // [2,2048,1024]
    const float* wqkv = (const float*)d_in[1];   // [1024,3072]
    const float* wo   = (const float*)d_in[2];   // [1024,1024]
    float* out = (float*)d_out;                  // [2,2048,1024] fp32
    char* ws = (char*)d_ws;

    u16* xb      = (u16*)(ws);                   // [4096][1024] bf16
    u16* wqkvT   = (u16*)(ws + 8388608);         // [3072][1024] bf16
    u16* woT     = (u16*)(ws + 14680064);        // [1024][1024] bf16
    u16* qb      = (u16*)(ws + 16777216);        // [32][2048][64] bf16
    u16* kb      = (u16*)(ws + 25165824);
    u16* vb      = (u16*)(ws + 33554432);
    float* li_ws = (float*)(ws + 41943040);      // [32][2048]
    float* cs_ws = (float*)(ws + 42205184);      // [32][2048]
    u16* valsb   = (u16*)(ws + 42467328);        // [4096][1024] bf16

    cast_f32_bf16<<<4096, 256, 0, stream>>>(x, xb, 1048576);
    transpose_cast<<<dim3(96, 32), dim3(32, 8), 0, stream>>>(wqkv, wqkvT, 1024, 3072);
    transpose_cast<<<dim3(32, 32), dim3(32, 8), 0, stream>>>(wo, woT, 1024, 1024);
    gemm_qkv<<<dim3(24, 32), 256, 0, stream>>>(xb, wqkvT, qb, kb, vb);
    attn_pass1<<<512, 256, 0, stream>>>(qb, kb, li_ws);
    attn_pass2<<<512, 256, 0, stream>>>(qb, kb, li_ws, cs_ws);
    scale_v<<<2048, 256, 0, stream>>>(vb, cs_ws, valsb);
    gemm_out<<<dim3(8, 32), 256, 0, stream>>>(valsb, woT, out);
}